// Round 3
// baseline (243.924 us; speedup 1.0000x reference)
//
#include <hip/hip_runtime.h>
#include <stdint.h>

// SVDQuant forward on MI355X:
//   y = Q4(x*smooth) @ Q4(Wres)^T + (x*smooth) @ lora_down @ lora_up^T + bias
// R3 structure (3 kernels):
//   K1 wq_kernel:  Wcat[n][0:2048] = bf16(fakequant(Wres)), [2048:2080]=bf16(lora_up),
//                  pad=0; blocks<256 also build ldT [32][2048] bf16 (lora_down^T)
//   K2 xq_kernel:  FUSED quant_x + lowrank. Per block: 16 rows.
//                  Phase A: x_s = x*smooth, per-64-group fakequant -> Xcat[:,0:2048]
//                           + bf16(x_s) staged in LDS (row stride 2056: 2-way bank aliasing)
//                  Phase B: t = x_s @ lora_down via MFMA from LDS -> Xcat[:,2048:2080]
//   K3 gemm_kernel: out = Xcat @ Wcat^T + bias  (K=2112, m97-style, global_load_lds
//                  width-16 staging + XOR swizzle)

typedef __attribute__((ext_vector_type(8))) short short8;
typedef __attribute__((ext_vector_type(8))) unsigned short ushort8;
typedef __attribute__((ext_vector_type(4))) unsigned short ushort4v;
typedef __attribute__((ext_vector_type(4))) float floatx4;

#define M_TOK 8192
#define K_IN  2048
#define N_OUT 2048
#define RANK  32
#define KC    2112   // 2048 quant + 32 lowrank + 32 zero pad  (33 * 64)
#define XS_STRIDE 2056  // LDS x_s row stride in shorts (+8 pad -> 4-bank row shift)

// round-to-nearest-even f32 -> bf16 (finite inputs only)
__device__ __forceinline__ unsigned short f2bf(float f) {
  unsigned int u = __float_as_uint(f);
  u += 0x7fff + ((u >> 16) & 1);
  return (unsigned short)(u >> 16);
}

// ---------------- K1: quant_w + ldT build -----------------------------------
__global__ __launch_bounds__(256) void wq_kernel(const float* __restrict__ wgt,
                                                 const float* __restrict__ lup,
                                                 const float* __restrict__ ld,
                                                 unsigned short* __restrict__ Wcat,
                                                 unsigned short* __restrict__ ldT) {
  int row = blockIdx.x, tid = threadIdx.x;
  const float4* wr = (const float4*)(wgt + (size_t)row * K_IN);
  float4 a0 = wr[tid * 2], a1 = wr[tid * 2 + 1];
  float v[8] = {a0.x, a0.y, a0.z, a0.w, a1.x, a1.y, a1.z, a1.w};
  float amax = 0.f;
#pragma unroll
  for (int i = 0; i < 8; ++i) amax = fmaxf(amax, fabsf(v[i]));
  amax = fmaxf(amax, __shfl_xor(amax, 1, 64));
  amax = fmaxf(amax, __shfl_xor(amax, 2, 64));
  amax = fmaxf(amax, __shfl_xor(amax, 4, 64));
  float scale = fmaxf(amax / 7.0f, 1e-8f);
  ushort8 q;
#pragma unroll
  for (int i = 0; i < 8; ++i) {
    float qq = rintf(v[i] / scale);   // IEEE div + RNE == jnp.round(g/scale)
    qq = fminf(fmaxf(qq, -7.f), 7.f);
    q[i] = f2bf(qq * scale);
  }
  *(ushort8*)(Wcat + (size_t)row * KC + tid * 8) = q;
  if (tid < 32)      Wcat[(size_t)row * KC + 2048 + tid] = f2bf(lup[row * RANK + tid]);
  else if (tid < 64) Wcat[(size_t)row * KC + 2048 + tid] = 0;
  // fold in ldT transpose: first 256 blocks handle 32*2048 elements
  if (row < 256) {
    int i = row * 256 + tid;
    int r = i >> 11, k = i & 2047;
    ldT[r * K_IN + k] = f2bf(ld[k * RANK + r]);
  }
}

// ---------------- K2: fused quant_x + lowrank -------------------------------
// 512 blocks x 256 thr (4 waves), 16 rows/block.
__global__ __launch_bounds__(256) void xq_kernel(const float* __restrict__ x,
                                                 const float* __restrict__ smooth,
                                                 const unsigned short* __restrict__ ldT,
                                                 unsigned short* __restrict__ Xcat) {
  __shared__ unsigned short xs[16 * XS_STRIDE];  // 64.25 KiB bf16 x_s
  __shared__ float red[4][16][32];               // 8 KiB
  int tid = threadIdx.x;
  int w = tid >> 6, lane = tid & 63, quad = lane >> 4, l16 = lane & 15;
  int rowbase = blockIdx.x * 16;

  // ---- Phase A: quantize. thread t -> row t>>4, col segment (t&15)*128 (2 groups of 64)
  {
    int r = tid >> 4, seg = tid & 15;
    const float4* xr = (const float4*)(x + (size_t)(rowbase + r) * K_IN + seg * 128);
    const float4* sr = (const float4*)(smooth + seg * 128);
    unsigned short* xc = Xcat + (size_t)(rowbase + r) * KC + seg * 128;
    unsigned short* xl = xs + r * XS_STRIDE + seg * 128;
#pragma unroll
    for (int g = 0; g < 2; ++g) {
      float v[64];
      float amax = 0.f;
#pragma unroll
      for (int j = 0; j < 16; ++j) {
        float4 a = xr[g * 16 + j];
        float4 s = sr[g * 16 + j];
        v[j * 4 + 0] = a.x * s.x; v[j * 4 + 1] = a.y * s.y;
        v[j * 4 + 2] = a.z * s.z; v[j * 4 + 3] = a.w * s.w;
        amax = fmaxf(amax, fmaxf(fmaxf(fabsf(v[j * 4]), fabsf(v[j * 4 + 1])),
                                 fmaxf(fabsf(v[j * 4 + 2]), fabsf(v[j * 4 + 3]))));
      }
      float scale = fmaxf(amax / 7.0f, 1e-8f);
#pragma unroll
      for (int j = 0; j < 8; ++j) {
        ushort8 q;
#pragma unroll
        for (int t = 0; t < 8; ++t) {
          float qq = rintf(v[j * 8 + t] / scale);
          qq = fminf(fmaxf(qq, -7.f), 7.f);
          q[t] = f2bf(qq * scale);
        }
        *(ushort8*)(xc + g * 64 + j * 8) = q;
        // bf16 x_s for the low-rank branch
        ushort8 sb;
#pragma unroll
        for (int t = 0; t < 8; ++t) sb[t] = f2bf(v[j * 8 + t]);
        *(ushort8*)(xl + g * 64 + j * 8) = sb;
      }
    }
    // zero pad Xcat[:, 2080:2112]: each thread writes 2 shorts of its row
    *(unsigned int*)(Xcat + (size_t)(rowbase + r) * KC + 2080 + seg * 2) = 0u;
  }
  __syncthreads();

  // ---- Phase B: t = x_s @ lora_down. wave w covers k in [w*512, w*512+512).
  floatx4 acc[2];
  acc[0] = (floatx4)0.f;
  acc[1] = (floatx4)0.f;
  int kbase = w * 512;
#pragma unroll 4
  for (int it = 0; it < 16; ++it) {
    int k = kbase + it * 32 + quad * 8;
    short8 af = *(const short8*)(xs + l16 * XS_STRIDE + k);
    short8 b0 = *(const short8*)(ldT + (size_t)l16 * K_IN + k);
    short8 b1 = *(const short8*)(ldT + (size_t)(16 + l16) * K_IN + k);
    acc[0] = __builtin_amdgcn_mfma_f32_16x16x32_bf16(af, b0, acc[0], 0, 0, 0);
    acc[1] = __builtin_amdgcn_mfma_f32_16x16x32_bf16(af, b1, acc[1], 0, 0, 0);
  }
  // C layout: row = quad*4 + r, col = l16 (+16 for acc[1])
#pragma unroll
  for (int nt = 0; nt < 2; ++nt)
#pragma unroll
    for (int r = 0; r < 4; ++r)
      red[w][quad * 4 + r][nt * 16 + l16] = acc[nt][r];
  __syncthreads();
  if (tid < 128) {
    int rl = tid >> 3, seg = tid & 7;  // row 0..15, col segment of 4
    ushort4v o;
#pragma unroll
    for (int j = 0; j < 4; ++j) {
      int c = seg * 4 + j;
      float s = red[0][rl][c] + red[1][rl][c] + red[2][rl][c] + red[3][rl][c];
      o[j] = f2bf(s);
    }
    *(ushort4v*)(Xcat + (size_t)(rowbase + rl) * KC + 2048 + seg * 4) = o;
  }
}

// ---------------- K3: main GEMM: out = Xcat @ Wcat^T + bias ----------------
__device__ __forceinline__ void gld_lds16(const unsigned short* g, unsigned short* l) {
  __builtin_amdgcn_global_load_lds(
      (const __attribute__((address_space(1))) unsigned int*)g,
      (__attribute__((address_space(3))) unsigned int*)l, 16, 0, 0);
}

__global__ __launch_bounds__(256) void gemm_kernel(const unsigned short* __restrict__ Xcat,
                                                   const unsigned short* __restrict__ Wcat,
                                                   const float* __restrict__ bias,
                                                   float* __restrict__ out) {
  __shared__ unsigned short smem[16384];  // A: 128x64, B: 128x64 bf16 (32 KiB)
  unsigned short* smemA = smem;
  unsigned short* smemB = smem + 8192;
  int tid = threadIdx.x;
  int w = tid >> 6, lane = tid & 63, quad = lane >> 4, l16 = lane & 15;
  int wm = w >> 1, wn = w & 1;
  int bM = blockIdx.y * 128, bN = blockIdx.x * 128;

  // staging: thread -> (row = tid/8, chunk pos = tid%8), fetch XOR-swizzled chunk
  int srow = tid >> 3;
  int cs = (tid & 7) ^ (srow & 7);
  const unsigned short* Ag = Xcat + (size_t)(bM + srow) * KC + cs * 8;
  const unsigned short* Bg = Wcat + (size_t)(bN + srow) * KC + cs * 8;

  // fragment LDS offsets (ushort units). row&7 == l16&7 for all tiles.
  int c0 = (quad ^ (l16 & 7)) * 8;
  int c1 = ((4 + quad) ^ (l16 & 7)) * 8;
  int arow[4], brow[4];
#pragma unroll
  for (int mt = 0; mt < 4; ++mt) arow[mt] = (wm * 64 + mt * 16 + l16) * 64;
#pragma unroll
  for (int nt = 0; nt < 4; ++nt) brow[nt] = (wn * 64 + nt * 16 + l16) * 64;

  floatx4 acc[4][4];
#pragma unroll
  for (int mt = 0; mt < 4; ++mt)
#pragma unroll
    for (int nt = 0; nt < 4; ++nt) acc[mt][nt] = (floatx4)0.f;

  for (int kt = 0; kt < 33; ++kt) {
    int k0 = kt * 64;
#pragma unroll
    for (int rd = 0; rd < 4; ++rd) {
      gld_lds16(Ag + (size_t)rd * 32 * KC + k0, smemA + rd * 2048 + w * 512);
      gld_lds16(Bg + (size_t)rd * 32 * KC + k0, smemB + rd * 2048 + w * 512);
    }
    __syncthreads();  // drains vmcnt (global_load_lds) before reads

    short8 af[4][2], bf[4][2];
#pragma unroll
    for (int mt = 0; mt < 4; ++mt) {
      af[mt][0] = *(const short8*)(smemA + arow[mt] + c0);
      af[mt][1] = *(const short8*)(smemA + arow[mt] + c1);
    }
#pragma unroll
    for (int nt = 0; nt < 4; ++nt) {
      bf[nt][0] = *(const short8*)(smemB + brow[nt] + c0);
      bf[nt][1] = *(const short8*)(smemB + brow[nt] + c1);
    }
#pragma unroll
    for (int kb = 0; kb < 2; ++kb)
#pragma unroll
      for (int mt = 0; mt < 4; ++mt)
#pragma unroll
        for (int nt = 0; nt < 4; ++nt)
          acc[mt][nt] = __builtin_amdgcn_mfma_f32_16x16x32_bf16(af[mt][kb], bf[nt][kb],
                                                                acc[mt][nt], 0, 0, 0);
    __syncthreads();  // protect LDS before next stage
  }

  // epilogue: + bias, store fp32
#pragma unroll
  for (int nt = 0; nt < 4; ++nt) {
    int col = bN + wn * 64 + nt * 16 + l16;
    float bv = bias[col];
#pragma unroll
    for (int mt = 0; mt < 4; ++mt) {
      int row = bM + wm * 64 + mt * 16 + quad * 4;
#pragma unroll
      for (int r = 0; r < 4; ++r)
        out[(size_t)(row + r) * N_OUT + col] = acc[mt][nt][r] + bv;
    }
  }
}

extern "C" void kernel_launch(void* const* d_in, const int* in_sizes, int n_in,
                              void* d_out, int out_size, void* d_ws, size_t ws_size,
                              hipStream_t stream) {
  const float* x      = (const float*)d_in[0];
  const float* wgt    = (const float*)d_in[1];
  const float* ld     = (const float*)d_in[2];
  const float* lup    = (const float*)d_in[3];
  const float* smooth = (const float*)d_in[4];
  const float* bias   = (const float*)d_in[5];
  float* out = (float*)d_out;

  unsigned short* Xcat = (unsigned short*)d_ws;                 // 8192*2112*2 = 34.6 MB
  unsigned short* Wcat = Xcat + (size_t)M_TOK * KC;             //  8.65 MB
  unsigned short* ldT  = Wcat + (size_t)N_OUT * KC;             //  128 KB

  hipLaunchKernelGGL(wq_kernel,   dim3(N_OUT),    dim3(256), 0, stream, wgt, lup, ld, Wcat, ldT);
  hipLaunchKernelGGL(xq_kernel,   dim3(M_TOK/16), dim3(256), 0, stream, x, smooth, ldT, Xcat);
  hipLaunchKernelGGL(gemm_kernel, dim3(N_OUT/128, M_TOK/128), dim3(256), 0, stream,
                     Xcat, Wcat, bias, out);
}

// Round 4
// 226.342 us; speedup vs baseline: 1.0777x; 1.0777x over previous
//
#include <hip/hip_runtime.h>
#include <stdint.h>

// SVDQuant forward on MI355X:
//   y = Q4(x*smooth) @ Q4(Wres)^T + (x*smooth) @ lora_down @ lora_up^T + bias
// R4 structure (2 kernels):
//   K1 prep_kernel (grid 2560):
//     blocks [0,512):   16 x-rows each. Phase A: coalesced fakequant(x*smooth)
//                       -> Xcat[:,0:2048] + bf16 x_s in LDS. Phase B: rank-32 MFMA
//                       t = x_s @ lora_down (B-frag loaded straight from lora_down,
//                       [k][r] layout, L2-hot) -> Xcat[:,2048:2080]; pad [2080:2112)=0.
//     blocks [512,2560): 1 w-row each: Wcat[:,0:2048]=fakequant(Wres),
//                       [2048:2080)=bf16(lora_up), [2080:2112)=0.
//   K2 gemm_kernel: out = Xcat @ Wcat^T + bias (K=2112, m97-style global_load_lds
//                   width-16 staging + XOR swizzle + XCD-aware block remap).

typedef __attribute__((ext_vector_type(8))) short short8;
typedef __attribute__((ext_vector_type(8))) unsigned short ushort8;
typedef __attribute__((ext_vector_type(4))) unsigned short ushort4v;
typedef __attribute__((ext_vector_type(4))) float floatx4;

#define M_TOK 8192
#define K_IN  2048
#define N_OUT 2048
#define RANK  32
#define KC    2112      // 2048 quant + 32 lowrank + 32 zero pad (33 * 64)
#define XS_STRIDE 2056  // LDS x_s row stride (shorts): +8 -> 4-bank row rotation

// round-to-nearest-even f32 -> bf16 (finite inputs only)
__device__ __forceinline__ unsigned short f2bf(float f) {
  unsigned int u = __float_as_uint(f);
  u += 0x7fff + ((u >> 16) & 1);
  return (unsigned short)(u >> 16);
}

// fakequant 8 values held by this lane; group of 64 = 8 consecutive lanes
__device__ __forceinline__ void quant8(const float* v, unsigned short* q) {
  float amax = 0.f;
#pragma unroll
  for (int i = 0; i < 8; ++i) amax = fmaxf(amax, fabsf(v[i]));
  amax = fmaxf(amax, __shfl_xor(amax, 1, 64));
  amax = fmaxf(amax, __shfl_xor(amax, 2, 64));
  amax = fmaxf(amax, __shfl_xor(amax, 4, 64));
  float scale = fmaxf(amax / 7.0f, 1e-8f);
#pragma unroll
  for (int i = 0; i < 8; ++i) {
    float qq = rintf(v[i] / scale);   // IEEE div + RNE == jnp.round(g/scale)
    qq = fminf(fmaxf(qq, -7.f), 7.f);
    q[i] = f2bf(qq * scale);
  }
}

// ---------------- K1: fused prep --------------------------------------------
__global__ __launch_bounds__(256) void prep_kernel(const float* __restrict__ x,
                                                   const float* __restrict__ smooth,
                                                   const float* __restrict__ wgt,
                                                   const float* __restrict__ ld,
                                                   const float* __restrict__ lup,
                                                   unsigned short* __restrict__ Xcat,
                                                   unsigned short* __restrict__ Wcat) {
  __shared__ unsigned short xs[16 * XS_STRIDE];  // 64.25 KiB bf16 x_s
  __shared__ float red[4][16][32];               // 8 KiB
  int tid = threadIdx.x;

  if (blockIdx.x >= 512) {
    // ---- W path: one row of Wres per block ----
    int row = blockIdx.x - 512;
    const float4* wr = (const float4*)(wgt + (size_t)row * K_IN);
    float4 a0 = wr[tid * 2], a1 = wr[tid * 2 + 1];
    float v[8] = {a0.x, a0.y, a0.z, a0.w, a1.x, a1.y, a1.z, a1.w};
    ushort8 q;
    quant8(v, (unsigned short*)&q);
    *(ushort8*)(Wcat + (size_t)row * KC + tid * 8) = q;
    if (tid < 32)      Wcat[(size_t)row * KC + 2048 + tid] = f2bf(lup[row * RANK + tid]);
    else if (tid < 64) Wcat[(size_t)row * KC + 2048 + tid] = 0;
    return;
  }

  // ---- X path: 16 rows per block ----
  int rowbase = blockIdx.x * 16;
  int w = tid >> 6, lane = tid & 63, quad = lane >> 4, l16 = lane & 15;

  // Phase A: coalesced quantize, one row per pass (256 thr x 8 elems = 2048)
  const float4* sr = (const float4*)smooth;
  float4 s0 = sr[tid * 2], s1 = sr[tid * 2 + 1];
#pragma unroll 2
  for (int r = 0; r < 16; ++r) {
    const float4* xr = (const float4*)(x + (size_t)(rowbase + r) * K_IN);
    float4 a0 = xr[tid * 2], a1 = xr[tid * 2 + 1];
    float v[8] = {a0.x * s0.x, a0.y * s0.y, a0.z * s0.z, a0.w * s0.w,
                  a1.x * s1.x, a1.y * s1.y, a1.z * s1.z, a1.w * s1.w};
    ushort8 q;
    quant8(v, (unsigned short*)&q);
    *(ushort8*)(Xcat + (size_t)(rowbase + r) * KC + tid * 8) = q;
    ushort8 sb;
#pragma unroll
    for (int t = 0; t < 8; ++t) sb[t] = f2bf(v[t]);
    *(ushort8*)(xs + r * XS_STRIDE + tid * 8) = sb;
  }
  // zero pad Xcat[:, 2080:2112): 16 threads x 4B per row
  *(unsigned int*)(Xcat + (size_t)(rowbase + (tid >> 4)) * KC + 2080 + (tid & 15) * 2) = 0u;
  __syncthreads();

  // Phase B: t = x_s @ lora_down. wave w covers k in [w*512, w*512+512).
  floatx4 acc[2];
  acc[0] = (floatx4)0.f;
  acc[1] = (floatx4)0.f;
  int kbase = w * 512;
#pragma unroll 2
  for (int it = 0; it < 16; ++it) {
    int k = kbase + it * 32 + quad * 8;
    short8 af = *(const short8*)(xs + l16 * XS_STRIDE + k);
    // B-frag straight from lora_down [k][r]: B[k=quad*8+j][n=l16 (+16)]
    short8 b0, b1;
#pragma unroll
    for (int j = 0; j < 8; ++j) {
      b0[j] = (short)f2bf(ld[(size_t)(k + j) * RANK + l16]);
      b1[j] = (short)f2bf(ld[(size_t)(k + j) * RANK + 16 + l16]);
    }
    acc[0] = __builtin_amdgcn_mfma_f32_16x16x32_bf16(af, b0, acc[0], 0, 0, 0);
    acc[1] = __builtin_amdgcn_mfma_f32_16x16x32_bf16(af, b1, acc[1], 0, 0, 0);
  }
  // C layout: row = quad*4 + r, col = l16 (+16 for acc[1])
#pragma unroll
  for (int nt = 0; nt < 2; ++nt)
#pragma unroll
    for (int r = 0; r < 4; ++r)
      red[w][quad * 4 + r][nt * 16 + l16] = acc[nt][r];
  __syncthreads();
  if (tid < 128) {
    int rl = tid >> 3, seg = tid & 7;  // row 0..15, col segment of 4
    ushort4v o;
#pragma unroll
    for (int j = 0; j < 4; ++j) {
      int c = seg * 4 + j;
      float s = red[0][rl][c] + red[1][rl][c] + red[2][rl][c] + red[3][rl][c];
      o[j] = f2bf(s);
    }
    *(ushort4v*)(Xcat + (size_t)(rowbase + rl) * KC + 2048 + seg * 4) = o;
  }
}

// ---------------- K2: main GEMM: out = Xcat @ Wcat^T + bias ----------------
__device__ __forceinline__ void gld_lds16(const unsigned short* g, unsigned short* l) {
  __builtin_amdgcn_global_load_lds(
      (const __attribute__((address_space(1))) unsigned int*)g,
      (__attribute__((address_space(3))) unsigned int*)l, 16, 0, 0);
}

__global__ __launch_bounds__(256) void gemm_kernel(const unsigned short* __restrict__ Xcat,
                                                   const unsigned short* __restrict__ Wcat,
                                                   const float* __restrict__ bias,
                                                   float* __restrict__ out) {
  __shared__ unsigned short smem[16384];  // A: 128x64, B: 128x64 bf16 (32 KiB)
  unsigned short* smemA = smem;
  unsigned short* smemB = smem + 8192;
  int tid = threadIdx.x;
  int w = tid >> 6, lane = tid & 63, quad = lane >> 4, l16 = lane & 15;
  int wm = w >> 1, wn = w & 1;

  // XCD/L2 swizzle: 64-block groups = 4 M-panels x 16 N-panels, M fastest.
  // B-panels revisit the same XCDs across groups -> stay L2-resident.
  int bid = blockIdx.x;
  int g = bid >> 6, r = bid & 63;
  int bN = (r >> 2) * 128;
  int bM = (g * 4 + (r & 3)) * 128;

  // staging: thread -> (row = tid/8, chunk pos = tid%8), fetch XOR-swizzled chunk
  int srow = tid >> 3;
  int cs = (tid & 7) ^ (srow & 7);
  const unsigned short* Ag = Xcat + (size_t)(bM + srow) * KC + cs * 8;
  const unsigned short* Bg = Wcat + (size_t)(bN + srow) * KC + cs * 8;

  // fragment LDS offsets (ushort units). row&7 == l16&7 for all tiles.
  int c0 = (quad ^ (l16 & 7)) * 8;
  int c1 = ((4 + quad) ^ (l16 & 7)) * 8;
  int arow[4], brow[4];
#pragma unroll
  for (int mt = 0; mt < 4; ++mt) arow[mt] = (wm * 64 + mt * 16 + l16) * 64;
#pragma unroll
  for (int nt = 0; nt < 4; ++nt) brow[nt] = (wn * 64 + nt * 16 + l16) * 64;

  floatx4 acc[4][4];
#pragma unroll
  for (int mt = 0; mt < 4; ++mt)
#pragma unroll
    for (int nt = 0; nt < 4; ++nt) acc[mt][nt] = (floatx4)0.f;

  for (int kt = 0; kt < 33; ++kt) {
    int k0 = kt * 64;
#pragma unroll
    for (int rd = 0; rd < 4; ++rd) {
      gld_lds16(Ag + (size_t)rd * 32 * KC + k0, smemA + rd * 2048 + w * 512);
      gld_lds16(Bg + (size_t)rd * 32 * KC + k0, smemB + rd * 2048 + w * 512);
    }
    __syncthreads();  // drains vmcnt (global_load_lds) before reads

    short8 af[4][2], bf[4][2];
#pragma unroll
    for (int mt = 0; mt < 4; ++mt) {
      af[mt][0] = *(const short8*)(smemA + arow[mt] + c0);
      af[mt][1] = *(const short8*)(smemA + arow[mt] + c1);
    }
#pragma unroll
    for (int nt = 0; nt < 4; ++nt) {
      bf[nt][0] = *(const short8*)(smemB + brow[nt] + c0);
      bf[nt][1] = *(const short8*)(smemB + brow[nt] + c1);
    }
#pragma unroll
    for (int kb = 0; kb < 2; ++kb)
#pragma unroll
      for (int mt = 0; mt < 4; ++mt)
#pragma unroll
        for (int nt = 0; nt < 4; ++nt)
          acc[mt][nt] = __builtin_amdgcn_mfma_f32_16x16x32_bf16(af[mt][kb], bf[nt][kb],
                                                                acc[mt][nt], 0, 0, 0);
    __syncthreads();  // protect LDS before next stage
  }

  // epilogue: + bias, store fp32
#pragma unroll
  for (int nt = 0; nt < 4; ++nt) {
    int col = bN + wn * 64 + nt * 16 + l16;
    float bv = bias[col];
#pragma unroll
    for (int mt = 0; mt < 4; ++mt) {
      int row = bM + wm * 64 + mt * 16 + quad * 4;
#pragma unroll
      for (int r2 = 0; r2 < 4; ++r2)
        out[(size_t)(row + r2) * N_OUT + col] = acc[mt][nt][r2] + bv;
    }
  }
}

extern "C" void kernel_launch(void* const* d_in, const int* in_sizes, int n_in,
                              void* d_out, int out_size, void* d_ws, size_t ws_size,
                              hipStream_t stream) {
  const float* x      = (const float*)d_in[0];
  const float* wgt    = (const float*)d_in[1];
  const float* ld     = (const float*)d_in[2];
  const float* lup    = (const float*)d_in[3];
  const float* smooth = (const float*)d_in[4];
  const float* bias   = (const float*)d_in[5];
  float* out = (float*)d_out;

  unsigned short* Xcat = (unsigned short*)d_ws;                 // 8192*2112*2 = 34.6 MB
  unsigned short* Wcat = Xcat + (size_t)M_TOK * KC;             //  8.65 MB

  hipLaunchKernelGGL(prep_kernel, dim3(512 + N_OUT), dim3(256), 0, stream,
                     x, smooth, wgt, ld, lup, Xcat, Wcat);
  hipLaunchKernelGGL(gemm_kernel, dim3((N_OUT / 128) * (M_TOK / 128)), dim3(256), 0, stream,
                     Xcat, Wcat, bias, out);
}